// Round 6
// baseline (613.952 us; speedup 1.0000x reference)
//
#include <hip/hip_runtime.h>
#include <hip/hip_bf16.h>

// Problem constants: T=8192, H=1024, D=1024, E=8, 2D=2048, K2=E*D=8192
#define T_DIM 8192
#define H_DIM 1024
#define D_DIM 1024
#define E_DIM 8
#define TWO_D 2048
#define K2 8192

#define ALPHA_C 1.702f
#define LIMIT_C 7.0f

typedef __attribute__((ext_vector_type(8))) short s8v;   // 8 bf16 = 4 VGPRs
typedef __attribute__((ext_vector_type(4))) float f4v;   // MFMA accumulator

__device__ __forceinline__ void g2l16(const void* g, void* l) {
    // async global->LDS, 16B per lane; LDS dest = wave-uniform base + lane*16
    __builtin_amdgcn_global_load_lds((const __attribute__((address_space(1))) void*)g,
                                     (__attribute__((address_space(3))) void*)l, 16, 0, 0);
}

__device__ __forceinline__ unsigned short f2bf(float f) {
    __hip_bfloat16 h = __float2bfloat16(f);
    return __builtin_bit_cast(unsigned short, h);
}

#define FEN asm volatile("" ::: "memory")
#define BARR { FEN; __builtin_amdgcn_s_barrier(); FEN; }
#define VMW0 asm volatile("s_waitcnt vmcnt(0)" ::: "memory")

// ---------------- convert kernels ----------------

__global__ void f32_to_bf16_kernel(const float* __restrict__ in,
                                   unsigned short* __restrict__ out, size_t n) {
    size_t i = ((size_t)blockIdx.x * blockDim.x + threadIdx.x) * 4;
    if (i + 3 < n) {
        float4 v = *(const float4*)(in + i);
        ushort4 o;
        o.x = f2bf(v.x); o.y = f2bf(v.y); o.z = f2bf(v.z); o.w = f2bf(v.w);
        *(ushort4*)(out + i) = o;
    }
}

// W1 [E][H][2D] -> w1b [E][2D'][H] bf16 with gate/up 16-col deinterleave.
// out[b*obs + remap(c)*ors + r] = bf16(in[b*ibs + r*cols + c]); 32x32 tiles.
__global__ void transpose_conv_kernel(const float* __restrict__ in,
                                      unsigned short* __restrict__ out,
                                      int cols, size_t ibs, size_t obs, size_t ors,
                                      int remap) {
    __shared__ float t[32][33];
    const int b = blockIdx.z;
    const int c0 = blockIdx.x * 32, r0 = blockIdx.y * 32;
    const int tx = threadIdx.x & 31, ty = threadIdx.x >> 5;  // ty in 0..7
    const float* ip = in + (size_t)b * ibs;
    #pragma unroll
    for (int i = 0; i < 4; ++i)
        t[ty + i * 8][tx] = ip[(size_t)(r0 + ty + i * 8) * cols + c0 + tx];
    __syncthreads();
    unsigned short* op = out + (size_t)b * obs;
    #pragma unroll
    for (int i = 0; i < 4; ++i) {
        int c = c0 + ty + i * 8;
        int nc = remap ? ((c & ~31) + ((c & 1) << 4) + ((c >> 1) & 15)) : c;
        op[(size_t)nc * ors + r0 + tx] = f2bf(t[tx][ty + i * 8]);
    }
}

// W3 [E][D][H] -> w3t tiled bf16: tile (nt, kt) = [128 H-rows][64 k-elems], laid out
// at ((nt*128 + kt)*8192), with XOR chunk swizzle baked in: element (hcol, k) goes to
// tile offset (hcol&127)*64 + ((k&63) ^ ((hcol&7)<<3)).  k = e*1024 + d.
__global__ void transpose_w3_tiled_kernel(const float* __restrict__ in,
                                          unsigned short* __restrict__ out) {
    __shared__ float t[32][33];
    const int e = blockIdx.z;
    const int c0 = blockIdx.x * 32;   // H cols
    const int r0 = blockIdx.y * 32;   // D rows
    const int tx = threadIdx.x & 31, ty = threadIdx.x >> 5;
    const float* ip = in + (size_t)e * D_DIM * H_DIM;
    #pragma unroll
    for (int i = 0; i < 4; ++i)
        t[ty + i * 8][tx] = ip[(size_t)(r0 + ty + i * 8) * H_DIM + c0 + tx];
    __syncthreads();
    #pragma unroll
    for (int i = 0; i < 4; ++i) {
        const int hcol = c0 + ty + i * 8;
        const int kk = e * D_DIM + r0 + tx;
        const int nt = hcol >> 7, rIn = hcol & 127;
        const int kt = kk >> 6, c = kk & 63;
        out[((size_t)nt * 128 + kt) * 8192 + rIn * 64 + (c ^ ((rIn & 7) << 3))] =
            f2bf(t[tx][ty + i * 8]);
    }
}

// ---------------- GEMM1: gu = hs @ W1[e] + b1[e]; act2 = rw*(up+1)*glu ----------------
// BK=64, XOR-swizzled LDS chunks. A: hsb [T][H] bf16. B: w1b [E][2D'][H] bf16
// (deinterleaved B^T). Output: act2t TILED bf16 (see gemm2 header) — each gemm1
// block's 128 rows x 64 D-cols output is exactly one (mt=bx, kt=e*16+nBase/128)
// tile, stored with the XOR chunk swizzle baked in.
// Grid: (x=m fastest, y=n, z=e) so 8 consecutive blocks (8 XCDs) share one B n-tile.

__global__ __launch_bounds__(256, 2) void gemm1_kernel(
    const short* __restrict__ Ag0,      // hsb
    const short* __restrict__ Bg0,      // w1b
    const float* __restrict__ b1,       // [E][2D] original interleaved
    const float* __restrict__ rw,       // [T][E]
    unsigned short* __restrict__ act2t) // tiled [64*128][128][64]
{
    const int e = blockIdx.z;
    const int mBase = blockIdx.x * 128;
    const int nBase = blockIdx.y * 128;
    const int tid = threadIdx.x;
    const int lane = tid & 63;
    const int wave = tid >> 6;
    const int wm = wave >> 1, wn = wave & 1;
    const int cq = lane & 15, quad = lane >> 4;

    __shared__ __align__(16) short As[128 * 64];
    __shared__ __align__(16) short Bs[128 * 64];

    const short* Ag = Ag0 + (size_t)mBase * H_DIM;
    const short* Bg = Bg0 + ((size_t)e * TWO_D + nBase) * H_DIM;

    f4v acc[4][4];
    #pragma unroll
    for (int mt = 0; mt < 4; ++mt)
        #pragma unroll
        for (int nt = 0; nt < 4; ++nt)
            acc[mt][nt] = (f4v){0.f, 0.f, 0.f, 0.f};

    const int srow8 = lane >> 3;                 // 0..7
    const int gco = ((lane & 7) ^ srow8) * 8;    // swizzled global k-offset (elements)
    const int cq7 = cq & 7;

    for (int k0 = 0; k0 < H_DIM; k0 += 64) {
        #pragma unroll
        for (int i = 0; i < 4; ++i) {
            const int r = wave * 32 + i * 8 + srow8;
            g2l16(Ag + (size_t)r * H_DIM + k0 + gco, As + (wave * 32 + i * 8) * 64);
            g2l16(Bg + (size_t)r * H_DIM + k0 + gco, Bs + (wave * 32 + i * 8) * 64);
        }
        __syncthreads();
        #pragma unroll
        for (int h = 0; h < 2; ++h) {
            s8v af[4], bf[4];
            const int pc = (((h << 2) + quad) ^ cq7) * 8;  // phys chunk offset (elements)
            #pragma unroll
            for (int i = 0; i < 4; ++i) {
                af[i] = *(const s8v*)(As + (wm * 64 + i * 16 + cq) * 64 + pc);
                bf[i] = *(const s8v*)(Bs + (wn * 64 + i * 16 + cq) * 64 + pc);
            }
            #pragma unroll
            for (int mt = 0; mt < 4; ++mt)
                #pragma unroll
                for (int nt = 0; nt < 4; ++nt)
                    acc[mt][nt] = __builtin_amdgcn_mfma_f32_16x16x32_bf16(
                        af[mt], bf[nt], acc[mt][nt], 0, 0, 0);
        }
        __syncthreads();
    }

    // epilogue: even nt tile = gate, odd nt tile = up for the same D-cols.
    float rwv[4][4];
    #pragma unroll
    for (int mt = 0; mt < 4; ++mt)
        #pragma unroll
        for (int r = 0; r < 4; ++r)
            rwv[mt][r] = rw[(size_t)(mBase + wm * 64 + mt * 16 + quad * 4 + r) * E_DIM + e];

    const int kt_blk = e * 16 + (nBase >> 7);
    unsigned short* tb = act2t + ((size_t)blockIdx.x * 128 + kt_blk) * 8192;

    #pragma unroll
    for (int p = 0; p < 2; ++p) {
        const int j = (((nBase + wn * 64 + p * 32) >> 5) << 4) + cq;   // D-col in [0,1024)
        const float gb = b1[(size_t)e * TWO_D + 2 * j];
        const float ub = b1[(size_t)e * TWO_D + 2 * j + 1];
        const int c = wn * 32 + p * 16 + cq;                           // col within tile
        #pragma unroll
        for (int mt = 0; mt < 4; ++mt) {
            #pragma unroll
            for (int r = 0; r < 4; ++r) {
                float gate = acc[mt][2 * p][r] + gb;
                float up   = acc[mt][2 * p + 1][r] + ub;
                gate = fminf(gate, LIMIT_C);
                up = fminf(fmaxf(up, -LIMIT_C), LIMIT_C);
                float glu = gate / (1.f + __expf(-ALPHA_C * gate));
                float a = (up + 1.f) * glu * rwv[mt][r];
                const int rIn = wm * 64 + mt * 16 + quad * 4 + r;      // row within tile
                tb[rIn * 64 + (c ^ ((rIn & 7) << 3))] = f2bf(a);
            }
        }
    }
}

// ---------------- GEMM2: out = act2 @ w3^T + sum_e rw*b3 (tiled operands) ----------
// A: act2t tiled [mt=64][kt=128][128][64] bf16 (XOR baked). B: w3t tiled
// [nt=8][kt=128][128][64] bf16 (XOR baked). Tile 256x128, BK=64, 8 waves (4m x 2n),
// per-wave 64x64 = acc[4][4]. Grid 256 = exactly 1 block/CU. id: m = id&31
// (XCD-grouped: the 8 n-sharers of an A panel have the same id%8 -> same XCD L2),
// n = id>>5. Staging is fully contiguous: each g2l16 copies 1 KB (8 rows x 64
// elems, phys-chunk order) with src = base + lane*8 — no strided gathers.
// 2-phase dbuf: stage t+1 before compute(t); vmcnt(0)+barrier after the MFMA
// cluster so the ~1300cy compute covers the fetch latency. Intensity: 48 KB/step
// for 4.19 MFLOP = 85 FLOP/B -> demand 39.6 B/cy/CU at MFMA floor (gemm1
// demonstrates ~50 deliverable).

__global__ __launch_bounds__(512, 1) void gemm2_kernel(
    const short* __restrict__ At,      // act2t
    const short* __restrict__ Bt,      // w3t
    const float* __restrict__ rw,      // [T][E]
    const float* __restrict__ b3,      // [E][H]
    float* __restrict__ out)           // [T][H]
{
    const int id = blockIdx.x;
    const int mIdx = id & 31;
    const int nIdx = id >> 5;
    const int tid = threadIdx.x;
    const int lane = tid & 63;
    const int wave = tid >> 6;          // 0..7
    const int wm = wave >> 1, wn = wave & 1;
    const int cq = lane & 15, quad = lane >> 4;
    const int cq7 = cq & 7;

    __shared__ __align__(16) short As[2][256 * 64];   // 64 KiB
    __shared__ __align__(16) short Bs[2][128 * 64];   // 32 KiB

    f4v acc[4][4];
    #pragma unroll
    for (int mt = 0; mt < 4; ++mt)
        #pragma unroll
        for (int nt = 0; nt < 4; ++nt)
            acc[mt][nt] = (f4v){0.f, 0.f, 0.f, 0.f};

    // contiguous tiled staging.
    // A: wave stages rows wave*32 .. +31 (4 x g2l16, 8 rows each);
    //    row R -> tile mt = 2*mIdx + (R>>7), row-in-tile R&127.
    // B: wave stages rows wave*16 .. +15 (2 x g2l16); tile nt = nIdx.
    const int lane8 = lane * 8;

#define G2STAGE(KT, BUF)                                                          \
    { const size_t _kt = (size_t)(KT);                                            \
      _Pragma("unroll")                                                           \
      for (int i = 0; i < 4; ++i) {                                               \
          const int R = wave * 32 + i * 8;                                        \
          const short* _s = At + ((size_t)(2 * mIdx + (R >> 7)) * 128 + _kt) * 8192 \
                          + (R & 127) * 64 + lane8;                               \
          g2l16(_s, &As[BUF][R * 64]);                                            \
      }                                                                           \
      _Pragma("unroll")                                                           \
      for (int i = 0; i < 2; ++i) {                                               \
          const int R = wave * 16 + i * 8;                                        \
          const short* _s = Bt + ((size_t)nIdx * 128 + _kt) * 8192 + R * 64 + lane8; \
          g2l16(_s, &Bs[BUF][R * 64]);                                            \
      } }

    // prologue: stage kt=0
    G2STAGE(0, 0);
    VMW0;
    BARR;

    int cur = 0;
    #pragma unroll 1
    for (int kt = 0; kt < 128; ++kt) {
        if (kt + 1 < 128) { G2STAGE(kt + 1, cur ^ 1); }
        FEN;
        const short* Ab = As[cur];
        const short* Bb = Bs[cur];
        __builtin_amdgcn_s_setprio(1);
        #pragma unroll
        for (int h = 0; h < 2; ++h) {
            s8v af[4], bf[4];
            const int pc = (((h << 2) + quad) ^ cq7) * 8;
            #pragma unroll
            for (int i = 0; i < 4; ++i) {
                af[i] = *(const s8v*)(Ab + (wm * 64 + i * 16 + cq) * 64 + pc);
                bf[i] = *(const s8v*)(Bb + (wn * 64 + i * 16 + cq) * 64 + pc);
            }
            #pragma unroll
            for (int mt = 0; mt < 4; ++mt)
                #pragma unroll
                for (int nt = 0; nt < 4; ++nt)
                    acc[mt][nt] = __builtin_amdgcn_mfma_f32_16x16x32_bf16(
                        af[mt], bf[nt], acc[mt][nt], 0, 0, 0);
        }
        __builtin_amdgcn_s_setprio(0);
        VMW0;   // staged tile kt+1 fully landed
        BARR;   // all waves done reading buf[cur] and staging
        cur ^= 1;
    }

    // epilogue: out = acc + sum_e rw[row][e] * b3[e][col]
    const int mBase = mIdx * 256;
    const int nBase = nIdx * 128;
    #pragma unroll
    for (int mt = 0; mt < 4; ++mt) {
        #pragma unroll
        for (int r = 0; r < 4; ++r) {
            const int row = mBase + wm * 64 + mt * 16 + quad * 4 + r;
            const float4 rwa = *(const float4*)(rw + (size_t)row * E_DIM);
            const float4 rwb = *(const float4*)(rw + (size_t)row * E_DIM + 4);
            #pragma unroll
            for (int nt = 0; nt < 4; ++nt) {
                const int col = nBase + wn * 64 + nt * 16 + cq;
                float bias = rwa.x * b3[0 * H_DIM + col] + rwa.y * b3[1 * H_DIM + col]
                           + rwa.z * b3[2 * H_DIM + col] + rwa.w * b3[3 * H_DIM + col]
                           + rwb.x * b3[4 * H_DIM + col] + rwb.y * b3[5 * H_DIM + col]
                           + rwb.z * b3[6 * H_DIM + col] + rwb.w * b3[7 * H_DIM + col];
                out[(size_t)row * H_DIM + col] = acc[mt][nt][r] + bias;
            }
        }
    }
}

// ---------------- launch ----------------

extern "C" void kernel_launch(void* const* d_in, const int* in_sizes, int n_in,
                              void* d_out, int out_size, void* d_ws, size_t ws_size,
                              hipStream_t stream) {
    const float* hs = (const float*)d_in[0];   // [T,H]
    const float* rw = (const float*)d_in[1];   // [T,E]
    const float* w1 = (const float*)d_in[2];   // [E,H,2D]
    const float* b1 = (const float*)d_in[3];   // [E,2D]
    const float* w3 = (const float*)d_in[4];   // [E,D,H]
    const float* b3 = (const float*)d_in[5];   // [E,H]
    float* out = (float*)d_out;

    char* ws = (char*)d_ws;
    unsigned short* hsb   = (unsigned short*)(ws);                          // 16 MB
    unsigned short* w1b   = (unsigned short*)(ws + ((size_t)16 << 20));     // 32 MB
    unsigned short* w3t   = (unsigned short*)(ws + ((size_t)48 << 20));     // 16 MB
    unsigned short* act2t = (unsigned short*)(ws + ((size_t)64 << 20));     // 128 MB

    // 1) hs -> bf16
    {
        size_t n = (size_t)T_DIM * H_DIM;  // 8388608
        f32_to_bf16_kernel<<<dim3(n / (256 * 4)), dim3(256), 0, stream>>>(hs, hsb, n);
    }
    // 2) W1 [E][H][2D] -> w1b [E][2D'][H] bf16 with gate/up 16-col deinterleave
    transpose_conv_kernel<<<dim3(TWO_D / 32, H_DIM / 32, E_DIM), dim3(256), 0, stream>>>(
        w1, w1b, TWO_D, (size_t)H_DIM * TWO_D, (size_t)TWO_D * H_DIM, (size_t)H_DIM, 1);
    // 3) W3 [E][D][H] -> w3t tiled bf16 (XOR chunk swizzle baked in)
    transpose_w3_tiled_kernel<<<dim3(H_DIM / 32, D_DIM / 32, E_DIM), dim3(256), 0, stream>>>(
        w3, w3t);
    // 4) GEMM1 + GLU epilogue -> act2t tiled (x=m fastest for XCD B-sharing)
    gemm1_kernel<<<dim3(T_DIM / 128, TWO_D / 128, E_DIM), dim3(256), 0, stream>>>(
        (const short*)hsb, (const short*)w1b, b1, rw, act2t);
    // 5) GEMM2 single-pass 256x128, tiled operands (256 blocks = 1/CU) -> out
    gemm2_kernel<<<dim3(256), dim3(512), 0, stream>>>(
        (const short*)act2t, (const short*)w3t, rw, b3, out);
}

// Round 7
// 581.451 us; speedup vs baseline: 1.0559x; 1.0559x over previous
//
#include <hip/hip_runtime.h>
#include <hip/hip_bf16.h>

// Problem constants: T=8192, H=1024, D=1024, E=8, 2D=2048, K2=E*D=8192
#define T_DIM 8192
#define H_DIM 1024
#define D_DIM 1024
#define E_DIM 8
#define TWO_D 2048
#define K2 8192

#define ALPHA_C 1.702f
#define LIMIT_C 7.0f

typedef __attribute__((ext_vector_type(8))) short s8v;   // 8 bf16 = 4 VGPRs
typedef __attribute__((ext_vector_type(4))) float f4v;   // MFMA accumulator

__device__ __forceinline__ void g2l16(const void* g, void* l) {
    // async global->LDS, 16B per lane; LDS dest = wave-uniform base + lane*16
    __builtin_amdgcn_global_load_lds((const __attribute__((address_space(1))) void*)g,
                                     (__attribute__((address_space(3))) void*)l, 16, 0, 0);
}

__device__ __forceinline__ unsigned short f2bf(float f) {
    __hip_bfloat16 h = __float2bfloat16(f);
    return __builtin_bit_cast(unsigned short, h);
}

// ---------------- convert kernels ----------------

__global__ void f32_to_bf16_kernel(const float* __restrict__ in,
                                   unsigned short* __restrict__ out, size_t n) {
    size_t i = ((size_t)blockIdx.x * blockDim.x + threadIdx.x) * 4;
    if (i + 3 < n) {
        float4 v = *(const float4*)(in + i);
        ushort4 o;
        o.x = f2bf(v.x); o.y = f2bf(v.y); o.z = f2bf(v.z); o.w = f2bf(v.w);
        *(ushort4*)(out + i) = o;
    }
}

// W1 [E][H][2D] -> w1b [E][2D'][H] bf16 with gate/up 16-col deinterleave.
// out[b*obs + remap(c)*ors + r] = bf16(in[b*ibs + r*cols + c]); 32x32 tiles.
__global__ void transpose_conv_kernel(const float* __restrict__ in,
                                      unsigned short* __restrict__ out,
                                      int cols, size_t ibs, size_t obs, size_t ors,
                                      int remap) {
    __shared__ float t[32][33];
    const int b = blockIdx.z;
    const int c0 = blockIdx.x * 32, r0 = blockIdx.y * 32;
    const int tx = threadIdx.x & 31, ty = threadIdx.x >> 5;  // ty in 0..7
    const float* ip = in + (size_t)b * ibs;
    #pragma unroll
    for (int i = 0; i < 4; ++i)
        t[ty + i * 8][tx] = ip[(size_t)(r0 + ty + i * 8) * cols + c0 + tx];
    __syncthreads();
    unsigned short* op = out + (size_t)b * obs;
    #pragma unroll
    for (int i = 0; i < 4; ++i) {
        int c = c0 + ty + i * 8;
        int nc = remap ? ((c & ~31) + ((c & 1) << 4) + ((c >> 1) & 15)) : c;
        op[(size_t)nc * ors + r0 + tx] = f2bf(t[tx][ty + i * 8]);
    }
}

// W3 [E][D][H] -> w3t tiled bf16: tile (nt, kt) = [128 H-rows][64 k-elems], laid out
// at ((nt*128 + kt)*8192), with XOR chunk swizzle baked in: element (hcol, k) goes to
// tile offset (hcol&127)*64 + ((k&63) ^ ((hcol&7)<<3)).  k = e*1024 + d.
__global__ void transpose_w3_tiled_kernel(const float* __restrict__ in,
                                          unsigned short* __restrict__ out) {
    __shared__ float t[32][33];
    const int e = blockIdx.z;
    const int c0 = blockIdx.x * 32;   // H cols
    const int r0 = blockIdx.y * 32;   // D rows
    const int tx = threadIdx.x & 31, ty = threadIdx.x >> 5;
    const float* ip = in + (size_t)e * D_DIM * H_DIM;
    #pragma unroll
    for (int i = 0; i < 4; ++i)
        t[ty + i * 8][tx] = ip[(size_t)(r0 + ty + i * 8) * H_DIM + c0 + tx];
    __syncthreads();
    #pragma unroll
    for (int i = 0; i < 4; ++i) {
        const int hcol = c0 + ty + i * 8;
        const int kk = e * D_DIM + r0 + tx;
        const int nt = hcol >> 7, rIn = hcol & 127;
        const int kt = kk >> 6, c = kk & 63;
        out[((size_t)nt * 128 + kt) * 8192 + rIn * 64 + (c ^ ((rIn & 7) << 3))] =
            f2bf(t[tx][ty + i * 8]);
    }
}

// out[t][h] += p0f (f32 partial from gemm2 ks=1) + sum_e rw[t][e]*b3[e][h]
__global__ void reduce_bias_kernel(const float* __restrict__ p0f,
                                   const float* __restrict__ rw,
                                   const float* __restrict__ b3,
                                   float* __restrict__ out) {
    const int t = blockIdx.x;
    const int h = threadIdx.x * 4;
    const size_t idx = (size_t)t * H_DIM + h;
    float r[E_DIM];
    #pragma unroll
    for (int e = 0; e < E_DIM; ++e) r[e] = rw[(size_t)t * E_DIM + e];
    float4 v = *(const float4*)(out + idx);
    float4 p = *(const float4*)(p0f + idx);
    v.x += p.x; v.y += p.y; v.z += p.z; v.w += p.w;
    #pragma unroll
    for (int e = 0; e < E_DIM; ++e) {
        float4 bb = *(const float4*)(b3 + (size_t)e * H_DIM + h);
        v.x += r[e] * bb.x; v.y += r[e] * bb.y; v.z += r[e] * bb.z; v.w += r[e] * bb.w;
    }
    *(float4*)(out + idx) = v;
}

// ---------------- GEMM1: 256x128 tile, 4 waves, single-buffer 48 KB -----------------
// gu = hs @ W1[e] + b1[e]; act2 = rw*(up+1)*glu, written TILED (act2t).
// A: hsb [T][H] bf16. B: w1b [E][2D'][H] bf16 (deinterleaved B^T).
// Intensity: 48 KB staged per 1024-cy MFMA step = 48 B/cy/CU demand — below the
// ~50 B/cy L2 delivery wall the 128^2 tile was pinned at (64 B/cy).
// Grid (x=m=32, y=n=16, z=e=8): A-panel sharers (fixed x) have id%8 = x%8 -> same XCD.

__global__ __launch_bounds__(256, 2) void gemm1_kernel(
    const short* __restrict__ Ag0,      // hsb
    const short* __restrict__ Bg0,      // w1b
    const float* __restrict__ b1,       // [E][2D] original interleaved
    const float* __restrict__ rw,       // [T][E]
    unsigned short* __restrict__ act2t) // tiled [64][128][128][64]
{
    const int e = blockIdx.z;
    const int mBase = blockIdx.x * 256;
    const int nBase = blockIdx.y * 128;
    const int tid = threadIdx.x;
    const int lane = tid & 63;
    const int wave = tid >> 6;           // 0..3
    const int wm = wave >> 1, wn = wave & 1;
    const int cq = lane & 15, quad = lane >> 4;
    const int cq7 = cq & 7;

    __shared__ __align__(16) short As[256 * 64];   // 32 KiB
    __shared__ __align__(16) short Bs[128 * 64];   // 16 KiB

    const short* Ag = Ag0 + (size_t)mBase * H_DIM;
    const short* Bg = Bg0 + ((size_t)e * TWO_D + nBase) * H_DIM;

    f4v acc[8][4];
    #pragma unroll
    for (int mt = 0; mt < 8; ++mt)
        #pragma unroll
        for (int nt = 0; nt < 4; ++nt)
            acc[mt][nt] = (f4v){0.f, 0.f, 0.f, 0.f};

    const int srow8 = lane >> 3;                 // 0..7
    const int gco = ((lane & 7) ^ srow8) * 8;    // swizzled global k-offset (elements)

    for (int k0 = 0; k0 < H_DIM; k0 += 64) {
        #pragma unroll
        for (int i = 0; i < 8; ++i) {
            const int rb = i * 32 + wave * 8;
            g2l16(Ag + (size_t)(rb + srow8) * H_DIM + k0 + gco, As + rb * 64);
        }
        #pragma unroll
        for (int i = 0; i < 4; ++i) {
            const int rb = i * 32 + wave * 8;
            g2l16(Bg + (size_t)(rb + srow8) * H_DIM + k0 + gco, Bs + rb * 64);
        }
        __syncthreads();
        #pragma unroll
        for (int h = 0; h < 2; ++h) {
            const int pc = (((h << 2) + quad) ^ cq7) * 8;  // phys chunk offset
            s8v bf[4];
            #pragma unroll
            for (int i = 0; i < 4; ++i)
                bf[i] = *(const s8v*)(Bs + (wn * 64 + i * 16 + cq) * 64 + pc);
            #pragma unroll
            for (int mt = 0; mt < 8; ++mt) {
                const s8v af = *(const s8v*)(As + (wm * 128 + mt * 16 + cq) * 64 + pc);
                #pragma unroll
                for (int nt = 0; nt < 4; ++nt)
                    acc[mt][nt] = __builtin_amdgcn_mfma_f32_16x16x32_bf16(
                        af, bf[nt], acc[mt][nt], 0, 0, 0);
            }
        }
        __syncthreads();
    }

    // epilogue: even nt = gate, odd nt = up for the same D-cols; write tiled+swizzled.
    const int kt = e * 16 + blockIdx.y;          // (e*1024 + j)>>6, j>>6 == blockIdx.y
    #pragma unroll
    for (int p = 0; p < 2; ++p) {
        const int j = (((nBase + wn * 64 + p * 32) >> 5) << 4) + cq;  // D-col [0,1024)
        const float gb = b1[(size_t)e * TWO_D + 2 * j];
        const float ub = b1[(size_t)e * TWO_D + 2 * j + 1];
        const int c = (wn * 2 + p) * 16 + cq;                         // j & 63
        #pragma unroll
        for (int mt = 0; mt < 8; ++mt) {
            #pragma unroll
            for (int r = 0; r < 4; ++r) {
                const int rIn = wm * 128 + mt * 16 + quad * 4 + r;    // 0..255
                const float rwv = rw[(size_t)(mBase + rIn) * E_DIM + e];
                float gate = acc[mt][2 * p][r] + gb;
                float up   = acc[mt][2 * p + 1][r] + ub;
                gate = fminf(gate, LIMIT_C);
                up = fminf(fmaxf(up, -LIMIT_C), LIMIT_C);
                float glu = gate / (1.f + __expf(-ALPHA_C * gate));
                float a = (up + 1.f) * glu * rwv;
                unsigned short* tb = act2t +
                    ((size_t)(blockIdx.x * 2 + (rIn >> 7)) * 128 + kt) * 8192;
                const int row = rIn & 127;
                tb[row * 64 + (c ^ ((row & 7) << 3))] = f2bf(a);
            }
        }
    }
}

// ---------------- GEMM2: 256x128 tile, split-K=2, tiled operands ----------------
// out_partial = act2 @ w3^T. A: act2t tiled [64][128][128][64] bf16 (XOR baked).
// B: w3t tiled [8][128][128][64] bf16. Grid 512 = 2 independent blocks/CU (the
// asynchrony that covers staging drains — r6's 1-block/CU barrier-locked the CU).
// id: m = id&31 (8 n-sharers of an A panel have same id%8 -> same XCD L2),
// n = (id>>5)&7, ks = id>>8 (K-slice of 4096 = 64 BK steps).
// Staging fully contiguous: each g2l16 = 1 KB (8 rows x 64 elems) at src+lane*16B.
// ks0 -> out (raw f32), ks1 -> p0f (f32); reduce adds partial + routed bias.

__global__ __launch_bounds__(256, 2) void gemm2_kernel(
    const short* __restrict__ At,      // act2t
    const short* __restrict__ Bt,      // w3t
    float* __restrict__ out,           // [T][H] raw acc (ks=0)
    float* __restrict__ p0f)           // [T][H] f32 partial (ks=1)
{
    const int id = blockIdx.x;
    const int mIdx = id & 31;
    const int nIdx = (id >> 5) & 7;
    const int ks = id >> 8;
    const int tid = threadIdx.x;
    const int lane = tid & 63;
    const int wave = tid >> 6;           // 0..3
    const int wm = wave >> 1, wn = wave & 1;
    const int cq = lane & 15, quad = lane >> 4;
    const int cq7 = cq & 7;
    const int lane8 = lane * 8;

    __shared__ __align__(16) short As[256 * 64];   // 32 KiB
    __shared__ __align__(16) short Bs[128 * 64];   // 16 KiB

    f4v acc[8][4];
    #pragma unroll
    for (int mt = 0; mt < 8; ++mt)
        #pragma unroll
        for (int nt = 0; nt < 4; ++nt)
            acc[mt][nt] = (f4v){0.f, 0.f, 0.f, 0.f};

    #pragma unroll 1
    for (int s = 0; s < 64; ++s) {
        const int kt = ks * 64 + s;
        #pragma unroll
        for (int i = 0; i < 8; ++i) {
            const int R = i * 32 + wave * 8;
            const short* src = At +
                ((size_t)(2 * mIdx + (R >> 7)) * 128 + kt) * 8192 + (R & 127) * 64 + lane8;
            g2l16(src, As + R * 64);
        }
        #pragma unroll
        for (int i = 0; i < 4; ++i) {
            const int R = i * 32 + wave * 8;
            const short* src = Bt + ((size_t)nIdx * 128 + kt) * 8192 + R * 64 + lane8;
            g2l16(src, Bs + R * 64);
        }
        __syncthreads();
        #pragma unroll
        for (int h = 0; h < 2; ++h) {
            const int pc = (((h << 2) + quad) ^ cq7) * 8;
            s8v bf[4];
            #pragma unroll
            for (int i = 0; i < 4; ++i)
                bf[i] = *(const s8v*)(Bs + (wn * 64 + i * 16 + cq) * 64 + pc);
            #pragma unroll
            for (int mt = 0; mt < 8; ++mt) {
                const s8v af = *(const s8v*)(As + (wm * 128 + mt * 16 + cq) * 64 + pc);
                #pragma unroll
                for (int nt = 0; nt < 4; ++nt)
                    acc[mt][nt] = __builtin_amdgcn_mfma_f32_16x16x32_bf16(
                        af, bf[nt], acc[mt][nt], 0, 0, 0);
            }
        }
        __syncthreads();
    }

    float* dst = (ks == 0) ? out : p0f;
    const int mBase = mIdx * 256;
    const int nBase = nIdx * 128;
    #pragma unroll
    for (int mt = 0; mt < 8; ++mt) {
        #pragma unroll
        for (int r = 0; r < 4; ++r) {
            const int row = mBase + wm * 128 + mt * 16 + quad * 4 + r;
            #pragma unroll
            for (int nt = 0; nt < 4; ++nt) {
                const int col = nBase + wn * 64 + nt * 16 + cq;
                dst[(size_t)row * H_DIM + col] = acc[mt][nt][r];
            }
        }
    }
}

// ---------------- launch ----------------

extern "C" void kernel_launch(void* const* d_in, const int* in_sizes, int n_in,
                              void* d_out, int out_size, void* d_ws, size_t ws_size,
                              hipStream_t stream) {
    const float* hs = (const float*)d_in[0];   // [T,H]
    const float* rw = (const float*)d_in[1];   // [T,E]
    const float* w1 = (const float*)d_in[2];   // [E,H,2D]
    const float* b1 = (const float*)d_in[3];   // [E,2D]
    const float* w3 = (const float*)d_in[4];   // [E,D,H]
    const float* b3 = (const float*)d_in[5];   // [E,H]
    float* out = (float*)d_out;

    char* ws = (char*)d_ws;
    unsigned short* hsb   = (unsigned short*)(ws);                          // 16 MB
    unsigned short* w1b   = (unsigned short*)(ws + ((size_t)16 << 20));     // 32 MB
    unsigned short* w3t   = (unsigned short*)(ws + ((size_t)48 << 20));     // 16 MB
    unsigned short* act2t = (unsigned short*)(ws + ((size_t)64 << 20));     // 128 MB
    // f32 partial reuses hsb+w1b region (dead after gemm1): 32 MB
    float* p0f = (float*)(ws);

    // 1) hs -> bf16
    {
        size_t n = (size_t)T_DIM * H_DIM;  // 8388608
        f32_to_bf16_kernel<<<dim3(n / (256 * 4)), dim3(256), 0, stream>>>(hs, hsb, n);
    }
    // 2) W1 [E][H][2D] -> w1b [E][2D'][H] bf16 with gate/up 16-col deinterleave
    transpose_conv_kernel<<<dim3(TWO_D / 32, H_DIM / 32, E_DIM), dim3(256), 0, stream>>>(
        w1, w1b, TWO_D, (size_t)H_DIM * TWO_D, (size_t)TWO_D * H_DIM, (size_t)H_DIM, 1);
    // 3) W3 [E][D][H] -> w3t tiled bf16 (XOR chunk swizzle baked in)
    transpose_w3_tiled_kernel<<<dim3(H_DIM / 32, D_DIM / 32, E_DIM), dim3(256), 0, stream>>>(
        w3, w3t);
    // 4) GEMM1 256x128 + GLU epilogue -> act2t tiled (x=m fastest; A XCD-grouped)
    gemm1_kernel<<<dim3(T_DIM / 256, TWO_D / 128, E_DIM), dim3(256), 0, stream>>>(
        (const short*)hsb, (const short*)w1b, b1, rw, act2t);
    // 5) GEMM2 256x128 split-K=2 (512 blocks = 2/CU): ks0 -> out, ks1 -> p0f
    gemm2_kernel<<<dim3(512), dim3(256), 0, stream>>>(
        (const short*)act2t, (const short*)w3t, out, p0f);
    // 6) out += p0f + sum_e rw*b3
    reduce_bias_kernel<<<dim3(T_DIM), dim3(H_DIM / 4), 0, stream>>>(
        p0f, rw, b3, out);
}

// Round 8
// 579.816 us; speedup vs baseline: 1.0589x; 1.0028x over previous
//
#include <hip/hip_runtime.h>
#include <hip/hip_bf16.h>

// Problem constants: T=8192, H=1024, D=1024, E=8, 2D=2048, K2=E*D=8192
#define T_DIM 8192
#define H_DIM 1024
#define D_DIM 1024
#define E_DIM 8
#define TWO_D 2048
#define K2 8192

#define ALPHA_C 1.702f
#define LIMIT_C 7.0f

typedef __attribute__((ext_vector_type(8))) short s8v;   // 8 bf16 = 4 VGPRs
typedef __attribute__((ext_vector_type(4))) float f4v;   // MFMA accumulator

__device__ __forceinline__ void g2l16(const void* g, void* l) {
    // async global->LDS, 16B per lane; LDS dest = wave-uniform base + lane*16
    __builtin_amdgcn_global_load_lds((const __attribute__((address_space(1))) void*)g,
                                     (__attribute__((address_space(3))) void*)l, 16, 0, 0);
}

__device__ __forceinline__ unsigned short f2bf(float f) {
    __hip_bfloat16 h = __float2bfloat16(f);
    return __builtin_bit_cast(unsigned short, h);
}

// ---------------- convert kernels ----------------

__global__ void f32_to_bf16_kernel(const float* __restrict__ in,
                                   unsigned short* __restrict__ out, size_t n) {
    size_t i = ((size_t)blockIdx.x * blockDim.x + threadIdx.x) * 4;
    if (i + 3 < n) {
        float4 v = *(const float4*)(in + i);
        ushort4 o;
        o.x = f2bf(v.x); o.y = f2bf(v.y); o.z = f2bf(v.z); o.w = f2bf(v.w);
        *(ushort4*)(out + i) = o;
    }
}

// W1 [E][H][2D] -> w1b [E][2D'][H] bf16 with gate/up 16-col deinterleave.
// out[b*obs + remap(c)*ors + r] = bf16(in[b*ibs + r*cols + c]); 32x32 tiles.
__global__ void transpose_conv_kernel(const float* __restrict__ in,
                                      unsigned short* __restrict__ out,
                                      int cols, size_t ibs, size_t obs, size_t ors,
                                      int remap) {
    __shared__ float t[32][33];
    const int b = blockIdx.z;
    const int c0 = blockIdx.x * 32, r0 = blockIdx.y * 32;
    const int tx = threadIdx.x & 31, ty = threadIdx.x >> 5;  // ty in 0..7
    const float* ip = in + (size_t)b * ibs;
    #pragma unroll
    for (int i = 0; i < 4; ++i)
        t[ty + i * 8][tx] = ip[(size_t)(r0 + ty + i * 8) * cols + c0 + tx];
    __syncthreads();
    unsigned short* op = out + (size_t)b * obs;
    #pragma unroll
    for (int i = 0; i < 4; ++i) {
        int c = c0 + ty + i * 8;
        int nc = remap ? ((c & ~31) + ((c & 1) << 4) + ((c >> 1) & 15)) : c;
        op[(size_t)nc * ors + r0 + tx] = f2bf(t[tx][ty + i * 8]);
    }
}

// W3 [E][D][H] -> w3t tiled bf16: tile (nt, kt) = [128 H-rows][64 k-elems], laid out
// at ((nt*128 + kt)*8192), with XOR chunk swizzle baked in: element (hcol, k) goes to
// tile offset (hcol&127)*64 + ((k&63) ^ ((hcol&7)<<3)).  k = e*1024 + d.
__global__ void transpose_w3_tiled_kernel(const float* __restrict__ in,
                                          unsigned short* __restrict__ out) {
    __shared__ float t[32][33];
    const int e = blockIdx.z;
    const int c0 = blockIdx.x * 32;   // H cols
    const int r0 = blockIdx.y * 32;   // D rows
    const int tx = threadIdx.x & 31, ty = threadIdx.x >> 5;
    const float* ip = in + (size_t)e * D_DIM * H_DIM;
    #pragma unroll
    for (int i = 0; i < 4; ++i)
        t[ty + i * 8][tx] = ip[(size_t)(r0 + ty + i * 8) * H_DIM + c0 + tx];
    __syncthreads();
    #pragma unroll
    for (int i = 0; i < 4; ++i) {
        const int hcol = c0 + ty + i * 8;
        const int kk = e * D_DIM + r0 + tx;
        const int nt = hcol >> 7, rIn = hcol & 127;
        const int kt = kk >> 6, c = kk & 63;
        out[((size_t)nt * 128 + kt) * 8192 + rIn * 64 + (c ^ ((rIn & 7) << 3))] =
            f2bf(t[tx][ty + i * 8]);
    }
}

// out[t][h] += p0f (f32 partial from gemm2 ks=1) + sum_e rw[t][e]*b3[e][h]
__global__ void reduce_bias_kernel(const float* __restrict__ p0f,
                                   const float* __restrict__ rw,
                                   const float* __restrict__ b3,
                                   float* __restrict__ out) {
    const int t = blockIdx.x;
    const int h = threadIdx.x * 4;
    const size_t idx = (size_t)t * H_DIM + h;
    float r[E_DIM];
    #pragma unroll
    for (int e = 0; e < E_DIM; ++e) r[e] = rw[(size_t)t * E_DIM + e];
    float4 v = *(const float4*)(out + idx);
    float4 p = *(const float4*)(p0f + idx);
    v.x += p.x; v.y += p.y; v.z += p.z; v.w += p.w;
    #pragma unroll
    for (int e = 0; e < E_DIM; ++e) {
        float4 bb = *(const float4*)(b3 + (size_t)e * H_DIM + h);
        v.x += r[e] * bb.x; v.y += r[e] * bb.y; v.z += r[e] * bb.z; v.w += r[e] * bb.w;
    }
    *(float4*)(out + idx) = v;
}

// ---------------- GEMM1 (r6 proven config: 269 µs, MfmaUtil 51.5) ----------------
// 128x128 tile, BK=64, 4 waves, single-buffer 32 KB, ~3 blocks/CU.
// gu = hs @ W1[e] + b1[e]; act2 = rw*(up+1)*glu, written TILED+swizzled (act2t).
// A: hsb [T][H] bf16. B: w1b [E][2D'][H] bf16 (deinterleaved B^T).
// Grid (x=m fastest, y=n, z=e): 8 consecutive blocks (8 XCDs) share one B n-tile.

__global__ __launch_bounds__(256, 2) void gemm1_kernel(
    const short* __restrict__ Ag0,      // hsb
    const short* __restrict__ Bg0,      // w1b
    const float* __restrict__ b1,       // [E][2D] original interleaved
    const float* __restrict__ rw,       // [T][E]
    unsigned short* __restrict__ act2t) // tiled [64][128][128][64]
{
    const int e = blockIdx.z;
    const int mBase = blockIdx.x * 128;
    const int nBase = blockIdx.y * 128;
    const int tid = threadIdx.x;
    const int lane = tid & 63;
    const int wave = tid >> 6;
    const int wm = wave >> 1, wn = wave & 1;
    const int cq = lane & 15, quad = lane >> 4;

    __shared__ __align__(16) short As[128 * 64];
    __shared__ __align__(16) short Bs[128 * 64];

    const short* Ag = Ag0 + (size_t)mBase * H_DIM;
    const short* Bg = Bg0 + ((size_t)e * TWO_D + nBase) * H_DIM;

    f4v acc[4][4];
    #pragma unroll
    for (int mt = 0; mt < 4; ++mt)
        #pragma unroll
        for (int nt = 0; nt < 4; ++nt)
            acc[mt][nt] = (f4v){0.f, 0.f, 0.f, 0.f};

    const int srow8 = lane >> 3;                 // 0..7
    const int gco = ((lane & 7) ^ srow8) * 8;    // swizzled global k-offset (elements)
    const int cq7 = cq & 7;

    for (int k0 = 0; k0 < H_DIM; k0 += 64) {
        #pragma unroll
        for (int i = 0; i < 4; ++i) {
            const int r = wave * 32 + i * 8 + srow8;
            g2l16(Ag + (size_t)r * H_DIM + k0 + gco, As + (wave * 32 + i * 8) * 64);
            g2l16(Bg + (size_t)r * H_DIM + k0 + gco, Bs + (wave * 32 + i * 8) * 64);
        }
        __syncthreads();
        #pragma unroll
        for (int h = 0; h < 2; ++h) {
            s8v af[4], bf[4];
            const int pc = (((h << 2) + quad) ^ cq7) * 8;  // phys chunk offset (elements)
            #pragma unroll
            for (int i = 0; i < 4; ++i) {
                af[i] = *(const s8v*)(As + (wm * 64 + i * 16 + cq) * 64 + pc);
                bf[i] = *(const s8v*)(Bs + (wn * 64 + i * 16 + cq) * 64 + pc);
            }
            #pragma unroll
            for (int mt = 0; mt < 4; ++mt)
                #pragma unroll
                for (int nt = 0; nt < 4; ++nt)
                    acc[mt][nt] = __builtin_amdgcn_mfma_f32_16x16x32_bf16(
                        af[mt], bf[nt], acc[mt][nt], 0, 0, 0);
        }
        __syncthreads();
    }

    // epilogue: even nt tile = gate, odd nt tile = up for the same D-cols.
    float rwv[4][4];
    #pragma unroll
    for (int mt = 0; mt < 4; ++mt)
        #pragma unroll
        for (int r = 0; r < 4; ++r)
            rwv[mt][r] = rw[(size_t)(mBase + wm * 64 + mt * 16 + quad * 4 + r) * E_DIM + e];

    const int kt_blk = e * 16 + blockIdx.y;
    unsigned short* tb = act2t + ((size_t)blockIdx.x * 128 + kt_blk) * 8192;

    #pragma unroll
    for (int p = 0; p < 2; ++p) {
        const int j = (((nBase + wn * 64 + p * 32) >> 5) << 4) + cq;   // D-col in [0,1024)
        const float gb = b1[(size_t)e * TWO_D + 2 * j];
        const float ub = b1[(size_t)e * TWO_D + 2 * j + 1];
        const int c = wn * 32 + p * 16 + cq;                           // j & 63
        #pragma unroll
        for (int mt = 0; mt < 4; ++mt) {
            #pragma unroll
            for (int r = 0; r < 4; ++r) {
                float gate = acc[mt][2 * p][r] + gb;
                float up   = acc[mt][2 * p + 1][r] + ub;
                gate = fminf(gate, LIMIT_C);
                up = fminf(fmaxf(up, -LIMIT_C), LIMIT_C);
                float glu = gate / (1.f + __expf(-ALPHA_C * gate));
                float a = (up + 1.f) * glu * rwv[mt][r];
                const int rIn = wm * 64 + mt * 16 + quad * 4 + r;      // row within tile
                tb[rIn * 64 + (c ^ ((rIn & 7) << 3))] = f2bf(a);
            }
        }
    }
}

// ---------------- GEMM2: 128x128 tile, split-K=2, tiled operands, 4 blocks/CU ----
// out_partial = act2 @ w3^T. A: act2t tiled [64][128][128][64] bf16 (XOR baked).
// B: w3t tiled [8][128][128][64] bf16. Structurally identical to gemm1's proven
// loop (single-buffer 32 KB, 2 syncthreads/step) with contiguous 1 KB g2l16
// staging (one 16 KB tile per operand per step). Grid 1024 = 64m x 8n x 2ks =
// exactly 4 blocks/CU (the r6 lesson: co-resident blocks cover staging drains).
// id: m = id&63 -> the 8 n-sharers of an A panel sit at ids == m (mod 8) -> same
// XCD; each act2t tile crosses L3 once chip-wide (128 MB total).
// ks0 -> out (raw f32), ks1 -> p0f; reduce adds partial + routed bias.

__global__ __launch_bounds__(256, 4) void gemm2_kernel(
    const short* __restrict__ At,      // act2t
    const short* __restrict__ Bt,      // w3t
    float* __restrict__ out,           // [T][H] raw acc (ks=0)
    float* __restrict__ p0f)           // [T][H] f32 partial (ks=1)
{
    const int id = blockIdx.x;
    const int mIdx = id & 63;
    const int nIdx = (id >> 6) & 7;
    const int ks = id >> 9;
    const int tid = threadIdx.x;
    const int lane = tid & 63;
    const int wave = tid >> 6;
    const int wm = wave >> 1, wn = wave & 1;
    const int cq = lane & 15, quad = lane >> 4;
    const int cq7 = cq & 7;
    const int lane8 = lane * 8;

    __shared__ __align__(16) short As[128 * 64];   // 16 KiB
    __shared__ __align__(16) short Bs[128 * 64];   // 16 KiB

    f4v acc[4][4];
    #pragma unroll
    for (int mt = 0; mt < 4; ++mt)
        #pragma unroll
        for (int nt = 0; nt < 4; ++nt)
            acc[mt][nt] = (f4v){0.f, 0.f, 0.f, 0.f};

    const short* Abase = At + (size_t)mIdx * 128 * 8192;
    const short* Bbase = Bt + (size_t)nIdx * 128 * 8192;

    #pragma unroll 1
    for (int s = 0; s < 64; ++s) {
        const int kt = ks * 64 + s;
        #pragma unroll
        for (int i = 0; i < 4; ++i) {
            const int R = wave * 32 + i * 8;
            g2l16(Abase + (size_t)kt * 8192 + R * 64 + lane8, As + R * 64);
            g2l16(Bbase + (size_t)kt * 8192 + R * 64 + lane8, Bs + R * 64);
        }
        __syncthreads();
        #pragma unroll
        for (int h = 0; h < 2; ++h) {
            const int pc = (((h << 2) + quad) ^ cq7) * 8;
            s8v af[4], bf[4];
            #pragma unroll
            for (int i = 0; i < 4; ++i) {
                af[i] = *(const s8v*)(As + (wm * 64 + i * 16 + cq) * 64 + pc);
                bf[i] = *(const s8v*)(Bs + (wn * 64 + i * 16 + cq) * 64 + pc);
            }
            #pragma unroll
            for (int mt = 0; mt < 4; ++mt)
                #pragma unroll
                for (int nt = 0; nt < 4; ++nt)
                    acc[mt][nt] = __builtin_amdgcn_mfma_f32_16x16x32_bf16(
                        af[mt], bf[nt], acc[mt][nt], 0, 0, 0);
        }
        __syncthreads();
    }

    float* dst = (ks == 0) ? out : p0f;
    const int mBase = mIdx * 128;
    const int nBase = nIdx * 128;
    #pragma unroll
    for (int mt = 0; mt < 4; ++mt) {
        #pragma unroll
        for (int r = 0; r < 4; ++r) {
            const int row = mBase + wm * 64 + mt * 16 + quad * 4 + r;
            #pragma unroll
            for (int nt = 0; nt < 4; ++nt) {
                const int col = nBase + wn * 64 + nt * 16 + cq;
                dst[(size_t)row * H_DIM + col] = acc[mt][nt][r];
            }
        }
    }
}

// ---------------- launch ----------------

extern "C" void kernel_launch(void* const* d_in, const int* in_sizes, int n_in,
                              void* d_out, int out_size, void* d_ws, size_t ws_size,
                              hipStream_t stream) {
    const float* hs = (const float*)d_in[0];   // [T,H]
    const float* rw = (const float*)d_in[1];   // [T,E]
    const float* w1 = (const float*)d_in[2];   // [E,H,2D]
    const float* b1 = (const float*)d_in[3];   // [E,2D]
    const float* w3 = (const float*)d_in[4];   // [E,D,H]
    const float* b3 = (const float*)d_in[5];   // [E,H]
    float* out = (float*)d_out;

    char* ws = (char*)d_ws;
    unsigned short* hsb   = (unsigned short*)(ws);                          // 16 MB
    unsigned short* w1b   = (unsigned short*)(ws + ((size_t)16 << 20));     // 32 MB
    unsigned short* w3t   = (unsigned short*)(ws + ((size_t)48 << 20));     // 16 MB
    unsigned short* act2t = (unsigned short*)(ws + ((size_t)64 << 20));     // 128 MB
    // f32 partial reuses hsb+w1b region (dead after gemm1): 32 MB
    float* p0f = (float*)(ws);

    // 1) hs -> bf16
    {
        size_t n = (size_t)T_DIM * H_DIM;  // 8388608
        f32_to_bf16_kernel<<<dim3(n / (256 * 4)), dim3(256), 0, stream>>>(hs, hsb, n);
    }
    // 2) W1 [E][H][2D] -> w1b [E][2D'][H] bf16 with gate/up 16-col deinterleave
    transpose_conv_kernel<<<dim3(TWO_D / 32, H_DIM / 32, E_DIM), dim3(256), 0, stream>>>(
        w1, w1b, TWO_D, (size_t)H_DIM * TWO_D, (size_t)TWO_D * H_DIM, (size_t)H_DIM, 1);
    // 3) W3 [E][D][H] -> w3t tiled bf16 (XOR chunk swizzle baked in)
    transpose_w3_tiled_kernel<<<dim3(H_DIM / 32, D_DIM / 32, E_DIM), dim3(256), 0, stream>>>(
        w3, w3t);
    // 4) GEMM1 128^2 (r6 proven) + GLU epilogue -> act2t tiled (x=m fastest)
    gemm1_kernel<<<dim3(T_DIM / 128, TWO_D / 128, E_DIM), dim3(256), 0, stream>>>(
        (const short*)hsb, (const short*)w1b, b1, rw, act2t);
    // 5) GEMM2 128^2 split-K=2 (1024 blocks = 4/CU): ks0 -> out, ks1 -> p0f
    gemm2_kernel<<<dim3(1024), dim3(256), 0, stream>>>(
        (const short*)act2t, (const short*)w3t, out, p0f);
    // 6) out += p0f + sum_e rw*b3
    reduce_bias_kernel<<<dim3(T_DIM), dim3(H_DIM / 4), 0, stream>>>(
        p0f, rw, b3, out);
}

// Round 9
// 555.244 us; speedup vs baseline: 1.1057x; 1.0443x over previous
//
#include <hip/hip_runtime.h>
#include <hip/hip_bf16.h>

// Problem constants: T=8192, H=1024, D=1024, E=8, 2D=2048, K2=E*D=8192
#define T_DIM 8192
#define H_DIM 1024
#define D_DIM 1024
#define E_DIM 8
#define TWO_D 2048
#define K2 8192

#define ALPHA_C 1.702f
#define LIMIT_C 7.0f

typedef __attribute__((ext_vector_type(8))) short s8v;   // 8 bf16 = 4 VGPRs
typedef __attribute__((ext_vector_type(4))) float f4v;   // MFMA accumulator

__device__ __forceinline__ void g2l16(const void* g, void* l) {
    // async global->LDS, 16B per lane; LDS dest = wave-uniform base + lane*16
    __builtin_amdgcn_global_load_lds((const __attribute__((address_space(1))) void*)g,
                                     (__attribute__((address_space(3))) void*)l, 16, 0, 0);
}

__device__ __forceinline__ unsigned short f2bf(float f) {
    __hip_bfloat16 h = __float2bfloat16(f);
    return __builtin_bit_cast(unsigned short, h);
}

// ---------------- convert kernels ----------------

__global__ void f32_to_bf16_kernel(const float* __restrict__ in,
                                   unsigned short* __restrict__ out, size_t n) {
    size_t i = ((size_t)blockIdx.x * blockDim.x + threadIdx.x) * 4;
    if (i + 3 < n) {
        float4 v = *(const float4*)(in + i);
        ushort4 o;
        o.x = f2bf(v.x); o.y = f2bf(v.y); o.z = f2bf(v.z); o.w = f2bf(v.w);
        *(ushort4*)(out + i) = o;
    }
}

// W1 [E][H][2D] -> w1b [E][2D'][H] bf16 with gate/up 16-col deinterleave.
// out[b*obs + remap(c)*ors + r] = bf16(in[b*ibs + r*cols + c]); 32x32 tiles.
__global__ void transpose_conv_kernel(const float* __restrict__ in,
                                      unsigned short* __restrict__ out,
                                      int cols, size_t ibs, size_t obs, size_t ors,
                                      int remap) {
    __shared__ float t[32][33];
    const int b = blockIdx.z;
    const int c0 = blockIdx.x * 32, r0 = blockIdx.y * 32;
    const int tx = threadIdx.x & 31, ty = threadIdx.x >> 5;  // ty in 0..7
    const float* ip = in + (size_t)b * ibs;
    #pragma unroll
    for (int i = 0; i < 4; ++i)
        t[ty + i * 8][tx] = ip[(size_t)(r0 + ty + i * 8) * cols + c0 + tx];
    __syncthreads();
    unsigned short* op = out + (size_t)b * obs;
    #pragma unroll
    for (int i = 0; i < 4; ++i) {
        int c = c0 + ty + i * 8;
        int nc = remap ? ((c & ~31) + ((c & 1) << 4) + ((c >> 1) & 15)) : c;
        op[(size_t)nc * ors + r0 + tx] = f2bf(t[tx][ty + i * 8]);
    }
}

// W3 [E][D][H] -> w3t tiled bf16: tile (nt, kt) = [128 H-rows][64 k-elems], laid out
// at ((nt*128 + kt)*8192), with XOR chunk swizzle baked in: element (hcol, k) goes to
// tile offset (hcol&127)*64 + ((k&63) ^ ((hcol&7)<<3)).  k = e*1024 + d.
__global__ void transpose_w3_tiled_kernel(const float* __restrict__ in,
                                          unsigned short* __restrict__ out) {
    __shared__ float t[32][33];
    const int e = blockIdx.z;
    const int c0 = blockIdx.x * 32;   // H cols
    const int r0 = blockIdx.y * 32;   // D rows
    const int tx = threadIdx.x & 31, ty = threadIdx.x >> 5;
    const float* ip = in + (size_t)e * D_DIM * H_DIM;
    #pragma unroll
    for (int i = 0; i < 4; ++i)
        t[ty + i * 8][tx] = ip[(size_t)(r0 + ty + i * 8) * H_DIM + c0 + tx];
    __syncthreads();
    #pragma unroll
    for (int i = 0; i < 4; ++i) {
        const int hcol = c0 + ty + i * 8;
        const int kk = e * D_DIM + r0 + tx;
        const int nt = hcol >> 7, rIn = hcol & 127;
        const int kt = kk >> 6, c = kk & 63;
        out[((size_t)nt * 128 + kt) * 8192 + rIn * 64 + (c ^ ((rIn & 7) << 3))] =
            f2bf(t[tx][ty + i * 8]);
    }
}

// out[t][h] += p0f (f32 partial from gemm2 ks=1) + sum_e rw[t][e]*b3[e][h]
__global__ void reduce_bias_kernel(const float* __restrict__ p0f,
                                   const float* __restrict__ rw,
                                   const float* __restrict__ b3,
                                   float* __restrict__ out) {
    const int t = blockIdx.x;
    const int h = threadIdx.x * 4;
    const size_t idx = (size_t)t * H_DIM + h;
    float r[E_DIM];
    #pragma unroll
    for (int e = 0; e < E_DIM; ++e) r[e] = rw[(size_t)t * E_DIM + e];
    float4 v = *(const float4*)(out + idx);
    float4 p = *(const float4*)(p0f + idx);
    v.x += p.x; v.y += p.y; v.z += p.z; v.w += p.w;
    #pragma unroll
    for (int e = 0; e < E_DIM; ++e) {
        float4 bb = *(const float4*)(b3 + (size_t)e * H_DIM + h);
        v.x += r[e] * bb.x; v.y += r[e] * bb.y; v.z += r[e] * bb.z; v.w += r[e] * bb.w;
    }
    *(float4*)(out + idx) = v;
}

// ---------------- GEMM1 (r8 proven config: 267 µs, MfmaUtil 51.7) ----------------
// 128x128 tile, BK=64, 4 waves, single-buffer 32 KB, ~3 blocks/CU.
// gu = hs @ W1[e] + b1[e]; act2 = rw*(up+1)*glu, written TILED+swizzled (act2t).
// A: hsb [T][H] bf16. B: w1b [E][2D'][H] bf16 (deinterleaved B^T).
// Grid (x=m fastest, y=n, z=e): 8 consecutive blocks (8 XCDs) share one B n-tile.

__global__ __launch_bounds__(256, 2) void gemm1_kernel(
    const short* __restrict__ Ag0,      // hsb
    const short* __restrict__ Bg0,      // w1b
    const float* __restrict__ b1,       // [E][2D] original interleaved
    const float* __restrict__ rw,       // [T][E]
    unsigned short* __restrict__ act2t) // tiled [64][128][128][64]
{
    const int e = blockIdx.z;
    const int mBase = blockIdx.x * 128;
    const int nBase = blockIdx.y * 128;
    const int tid = threadIdx.x;
    const int lane = tid & 63;
    const int wave = tid >> 6;
    const int wm = wave >> 1, wn = wave & 1;
    const int cq = lane & 15, quad = lane >> 4;

    __shared__ __align__(16) short As[128 * 64];
    __shared__ __align__(16) short Bs[128 * 64];

    const short* Ag = Ag0 + (size_t)mBase * H_DIM;
    const short* Bg = Bg0 + ((size_t)e * TWO_D + nBase) * H_DIM;

    f4v acc[4][4];
    #pragma unroll
    for (int mt = 0; mt < 4; ++mt)
        #pragma unroll
        for (int nt = 0; nt < 4; ++nt)
            acc[mt][nt] = (f4v){0.f, 0.f, 0.f, 0.f};

    const int srow8 = lane >> 3;                 // 0..7
    const int gco = ((lane & 7) ^ srow8) * 8;    // swizzled global k-offset (elements)
    const int cq7 = cq & 7;

    for (int k0 = 0; k0 < H_DIM; k0 += 64) {
        #pragma unroll
        for (int i = 0; i < 4; ++i) {
            const int r = wave * 32 + i * 8 + srow8;
            g2l16(Ag + (size_t)r * H_DIM + k0 + gco, As + (wave * 32 + i * 8) * 64);
            g2l16(Bg + (size_t)r * H_DIM + k0 + gco, Bs + (wave * 32 + i * 8) * 64);
        }
        __syncthreads();
        #pragma unroll
        for (int h = 0; h < 2; ++h) {
            s8v af[4], bf[4];
            const int pc = (((h << 2) + quad) ^ cq7) * 8;  // phys chunk offset (elements)
            #pragma unroll
            for (int i = 0; i < 4; ++i) {
                af[i] = *(const s8v*)(As + (wm * 64 + i * 16 + cq) * 64 + pc);
                bf[i] = *(const s8v*)(Bs + (wn * 64 + i * 16 + cq) * 64 + pc);
            }
            #pragma unroll
            for (int mt = 0; mt < 4; ++mt)
                #pragma unroll
                for (int nt = 0; nt < 4; ++nt)
                    acc[mt][nt] = __builtin_amdgcn_mfma_f32_16x16x32_bf16(
                        af[mt], bf[nt], acc[mt][nt], 0, 0, 0);
        }
        __syncthreads();
    }

    // epilogue: even nt tile = gate, odd nt tile = up for the same D-cols.
    float rwv[4][4];
    #pragma unroll
    for (int mt = 0; mt < 4; ++mt)
        #pragma unroll
        for (int r = 0; r < 4; ++r)
            rwv[mt][r] = rw[(size_t)(mBase + wm * 64 + mt * 16 + quad * 4 + r) * E_DIM + e];

    const int kt_blk = e * 16 + blockIdx.y;
    unsigned short* tb = act2t + ((size_t)blockIdx.x * 128 + kt_blk) * 8192;

    #pragma unroll
    for (int p = 0; p < 2; ++p) {
        const int j = (((nBase + wn * 64 + p * 32) >> 5) << 4) + cq;   // D-col in [0,1024)
        const float gb = b1[(size_t)e * TWO_D + 2 * j];
        const float ub = b1[(size_t)e * TWO_D + 2 * j + 1];
        const int c = wn * 32 + p * 16 + cq;                           // j & 63
        #pragma unroll
        for (int mt = 0; mt < 4; ++mt) {
            #pragma unroll
            for (int r = 0; r < 4; ++r) {
                float gate = acc[mt][2 * p][r] + gb;
                float up   = acc[mt][2 * p + 1][r] + ub;
                gate = fminf(gate, LIMIT_C);
                up = fminf(fmaxf(up, -LIMIT_C), LIMIT_C);
                float glu = gate / (1.f + __expf(-ALPHA_C * gate));
                float a = (up + 1.f) * glu * rwv[mt][r];
                const int rIn = wm * 64 + mt * 16 + quad * 4 + r;      // row within tile
                tb[rIn * 64 + (c ^ ((rIn & 7) << 3))] = f2bf(a);
            }
        }
    }
}

// ---------------- GEMM2 (r7 proven config: ~213 µs) ----------------
// 256x128 tile, split-K=2, tiled operands, 2 blocks/CU.
// out_partial = act2 @ w3^T. A: act2t tiled [64][128][128][64] bf16 (XOR baked).
// B: w3t tiled [8][128][128][64] bf16. Grid 512 = 32m x 8n x 2ks = 2 blocks/CU.
// id: m = id&31 (8 n-sharers of an A panel have same id%8 -> same XCD L2),
// n = (id>>5)&7, ks = id>>8 (K-slice of 4096 = 64 BK steps).
// Staging fully contiguous: each g2l16 = 1 KB (8 rows x 64 elems) at src+lane*16B.
// ks0 -> out (raw f32), ks1 -> p0f (f32); reduce adds partial + routed bias.

__global__ __launch_bounds__(256, 2) void gemm2_kernel(
    const short* __restrict__ At,      // act2t
    const short* __restrict__ Bt,      // w3t
    float* __restrict__ out,           // [T][H] raw acc (ks=0)
    float* __restrict__ p0f)           // [T][H] f32 partial (ks=1)
{
    const int id = blockIdx.x;
    const int mIdx = id & 31;
    const int nIdx = (id >> 5) & 7;
    const int ks = id >> 8;
    const int tid = threadIdx.x;
    const int lane = tid & 63;
    const int wave = tid >> 6;           // 0..3
    const int wm = wave >> 1, wn = wave & 1;
    const int cq = lane & 15, quad = lane >> 4;
    const int cq7 = cq & 7;
    const int lane8 = lane * 8;

    __shared__ __align__(16) short As[256 * 64];   // 32 KiB
    __shared__ __align__(16) short Bs[128 * 64];   // 16 KiB

    f4v acc[8][4];
    #pragma unroll
    for (int mt = 0; mt < 8; ++mt)
        #pragma unroll
        for (int nt = 0; nt < 4; ++nt)
            acc[mt][nt] = (f4v){0.f, 0.f, 0.f, 0.f};

    #pragma unroll 1
    for (int s = 0; s < 64; ++s) {
        const int kt = ks * 64 + s;
        #pragma unroll
        for (int i = 0; i < 8; ++i) {
            const int R = i * 32 + wave * 8;
            const short* src = At +
                ((size_t)(2 * mIdx + (R >> 7)) * 128 + kt) * 8192 + (R & 127) * 64 + lane8;
            g2l16(src, As + R * 64);
        }
        #pragma unroll
        for (int i = 0; i < 4; ++i) {
            const int R = i * 32 + wave * 8;
            const short* src = Bt + ((size_t)nIdx * 128 + kt) * 8192 + R * 64 + lane8;
            g2l16(src, Bs + R * 64);
        }
        __syncthreads();
        #pragma unroll
        for (int h = 0; h < 2; ++h) {
            const int pc = (((h << 2) + quad) ^ cq7) * 8;
            s8v bf[4];
            #pragma unroll
            for (int i = 0; i < 4; ++i)
                bf[i] = *(const s8v*)(Bs + (wn * 64 + i * 16 + cq) * 64 + pc);
            #pragma unroll
            for (int mt = 0; mt < 8; ++mt) {
                const s8v af = *(const s8v*)(As + (wm * 128 + mt * 16 + cq) * 64 + pc);
                #pragma unroll
                for (int nt = 0; nt < 4; ++nt)
                    acc[mt][nt] = __builtin_amdgcn_mfma_f32_16x16x32_bf16(
                        af, bf[nt], acc[mt][nt], 0, 0, 0);
            }
        }
        __syncthreads();
    }

    float* dst = (ks == 0) ? out : p0f;
    const int mBase = mIdx * 256;
    const int nBase = nIdx * 128;
    #pragma unroll
    for (int mt = 0; mt < 8; ++mt) {
        #pragma unroll
        for (int r = 0; r < 4; ++r) {
            const int row = mBase + wm * 128 + mt * 16 + quad * 4 + r;
            #pragma unroll
            for (int nt = 0; nt < 4; ++nt) {
                const int col = nBase + wn * 64 + nt * 16 + cq;
                dst[(size_t)row * H_DIM + col] = acc[mt][nt][r];
            }
        }
    }
}

// ---------------- launch ----------------

extern "C" void kernel_launch(void* const* d_in, const int* in_sizes, int n_in,
                              void* d_out, int out_size, void* d_ws, size_t ws_size,
                              hipStream_t stream) {
    const float* hs = (const float*)d_in[0];   // [T,H]
    const float* rw = (const float*)d_in[1];   // [T,E]
    const float* w1 = (const float*)d_in[2];   // [E,H,2D]
    const float* b1 = (const float*)d_in[3];   // [E,2D]
    const float* w3 = (const float*)d_in[4];   // [E,D,H]
    const float* b3 = (const float*)d_in[5];   // [E,H]
    float* out = (float*)d_out;

    char* ws = (char*)d_ws;
    unsigned short* hsb   = (unsigned short*)(ws);                          // 16 MB
    unsigned short* w1b   = (unsigned short*)(ws + ((size_t)16 << 20));     // 32 MB
    unsigned short* w3t   = (unsigned short*)(ws + ((size_t)48 << 20));     // 16 MB
    unsigned short* act2t = (unsigned short*)(ws + ((size_t)64 << 20));     // 128 MB
    // f32 partial reuses hsb+w1b region (dead after gemm1): 32 MB
    float* p0f = (float*)(ws);

    // 1) hs -> bf16
    {
        size_t n = (size_t)T_DIM * H_DIM;  // 8388608
        f32_to_bf16_kernel<<<dim3(n / (256 * 4)), dim3(256), 0, stream>>>(hs, hsb, n);
    }
    // 2) W1 [E][H][2D] -> w1b [E][2D'][H] bf16 with gate/up 16-col deinterleave
    transpose_conv_kernel<<<dim3(TWO_D / 32, H_DIM / 32, E_DIM), dim3(256), 0, stream>>>(
        w1, w1b, TWO_D, (size_t)H_DIM * TWO_D, (size_t)TWO_D * H_DIM, (size_t)H_DIM, 1);
    // 3) W3 [E][D][H] -> w3t tiled bf16 (XOR chunk swizzle baked in)
    transpose_w3_tiled_kernel<<<dim3(H_DIM / 32, D_DIM / 32, E_DIM), dim3(256), 0, stream>>>(
        w3, w3t);
    // 4) GEMM1 128^2 (r8 proven) + GLU epilogue -> act2t tiled (x=m fastest)
    gemm1_kernel<<<dim3(T_DIM / 128, TWO_D / 128, E_DIM), dim3(256), 0, stream>>>(
        (const short*)hsb, (const short*)w1b, b1, rw, act2t);
    // 5) GEMM2 256x128 split-K=2 (512 blocks = 2/CU): ks0 -> out, ks1 -> p0f
    gemm2_kernel<<<dim3(512), dim3(256), 0, stream>>>(
        (const short*)act2t, (const short*)w3t, out, p0f);
    // 6) out += p0f + sum_e rw*b3
    reduce_bias_kernel<<<dim3(T_DIM), dim3(H_DIM / 4), 0, stream>>>(
        p0f, rw, b3, out);
}